// Round 2
// baseline (433.683 us; speedup 1.0000x reference)
//
#include <hip/hip_runtime.h>
#include <hip/hip_fp16.h>

#define R_TOTAL 2097152
#define M_DEPTH 8
#define C_CH 16

// 16 halves = 32 bytes, loaded as two 16B vector loads.
struct H16 { float4 a, b; };

// ---------------------------------------------------------------------------
// Repack [M, C, H, W] f32 -> [M, H, W, C] fp16. One thread per texel (m,y,x):
// 16 coalesced plane reads, convert, one 32B store.
// ---------------------------------------------------------------------------
__global__ __launch_bounds__(256) void repack_fp16_kernel(const float* __restrict__ src,
                                                          __half* __restrict__ dst,
                                                          int lgHW) {
    int t = blockIdx.x * blockDim.x + threadIdx.x;   // index over M*H*W
    int HW = 1 << lgHW;
    int m  = t >> lgHW;
    int p  = t & (HW - 1);                           // y*W + x
    const float* s = src + (size_t)m * C_CH * HW + p;
    union { __half h[C_CH]; float4 f[2]; } u;
#pragma unroll
    for (int c = 0; c < C_CH; ++c) u.h[c] = __float2half(s[(size_t)c * HW]);
    float4* d4 = (float4*)(dst + (size_t)t * C_CH);
    d4[0] = u.f[0];
    d4[1] = u.f[1];
}

// ---------------------------------------------------------------------------
// Trilinear sampler on packed fp16 [M, H, W, C] textures. 2 samples / thread.
// ---------------------------------------------------------------------------
__device__ inline void accum_pair(const H16& A, const H16& B, float w, float wx,
                                  float acc[C_CH]) {
    const __half2* ha = (const __half2*)&A;
    const __half2* hb = (const __half2*)&B;
#pragma unroll
    for (int k = 0; k < 8; ++k) {
        float2 fa = __half22float2(ha[k]);
        float2 fb = __half22float2(hb[k]);
        acc[2 * k + 0] += w * (fa.x + wx * (fb.x - fa.x));
        acc[2 * k + 1] += w * (fa.y + wx * (fb.y - fa.y));
    }
}

__device__ inline void sample_one(float uu, float vv, float z, int which,
                                  const __half* __restrict__ tex0p,
                                  const __half* __restrict__ tex1p,
                                  float acc[C_CH]) {
    const __half* tex = (which == 0) ? tex0p : tex1p;
    int   Wm1 = (which == 0) ? 511 : 255;
    int   W   = Wm1 + 1;
    float fw  = (float)Wm1;

    float x = fminf(fmaxf((uu + 1.0f) * 0.5f * fw, 0.0f), fw);
    float y = fminf(fmaxf((vv + 1.0f) * 0.5f * fw, 0.0f), fw);
    float d = fminf(fmaxf((z + 1.0f) * 0.5f * 7.0f, 0.0f), 7.0f);

    int x0 = (int)x, y0 = (int)y, d0 = (int)d;
    int x1 = min(x0 + 1, Wm1), y1 = min(y0 + 1, Wm1), d1 = min(d0 + 1, 7);
    float wx = x - (float)x0, wy = y - (float)y0, wd = d - (float)d0;

    float w_d[2] = {1.0f - wd, wd};
    float w_y[2] = {1.0f - wy, wy};
    int   ds[2]  = {d0, d1};
    int   ys[2]  = {y0, y1};

    // Issue all 8 corner loads (16 x dwordx4) up front, then blend.
    H16 va[2][2], vb[2][2];
#pragma unroll
    for (int a = 0; a < 2; ++a)
#pragma unroll
        for (int b = 0; b < 2; ++b) {
            const __half* base = tex + (size_t)(ds[a] * W + ys[b]) * W * C_CH;
            va[a][b] = *(const H16*)(base + (size_t)x0 * C_CH);
            vb[a][b] = *(const H16*)(base + (size_t)x1 * C_CH);
        }
#pragma unroll
    for (int a = 0; a < 2; ++a)
#pragma unroll
        for (int b = 0; b < 2; ++b)
            accum_pair(va[a][b], vb[a][b], w_d[a] * w_y[b], wx, acc);
}

__global__ __launch_bounds__(256) void sample_packed_fp16(
    const float* __restrict__ uv, const int* __restrict__ idcs,
    const float* __restrict__ sid, const __half* __restrict__ tex0p,
    const __half* __restrict__ tex1p, float* __restrict__ out) {
    int t  = blockIdx.x * blockDim.x + threadIdx.x;  // one thread = 2 samples
    int i0 = 2 * t;

    float4 uv2 = ((const float4*)uv)[t];             // u0,v0,u1,v1
    float2 z2  = ((const float2*)sid)[t];
    int2   w2  = ((const int2*)idcs)[t];

    float acc0[C_CH], acc1[C_CH];
#pragma unroll
    for (int c = 0; c < C_CH; ++c) { acc0[c] = 0.0f; acc1[c] = 0.0f; }

    sample_one(uv2.x, uv2.y, z2.x, w2.x, tex0p, tex1p, acc0);
    sample_one(uv2.z, uv2.w, z2.y, w2.y, tex0p, tex1p, acc1);

#pragma unroll
    for (int c = 0; c < C_CH; ++c) {
        float2 o = make_float2(acc0[c], acc1[c]);
        *(float2*)(out + (size_t)c * R_TOTAL + i0) = o;
    }
}

// ---------------------------------------------------------------------------
// Fallback: sample directly from [M, C, H, W] f32 (if workspace too small).
// ---------------------------------------------------------------------------
__global__ __launch_bounds__(256) void sample_direct(
    const float2* __restrict__ uv, const int* __restrict__ idcs,
    const float* __restrict__ sid, const float* __restrict__ tex0,
    const float* __restrict__ tex1, float* __restrict__ out) {
    int i = blockIdx.x * blockDim.x + threadIdx.x;

    float2 t  = uv[i];
    float  z  = sid[i];
    int which = idcs[i];

    const float* tex = (which == 0) ? tex0 : tex1;
    int   Wm1 = (which == 0) ? 511 : 255;
    int   W   = Wm1 + 1;
    float fw  = (float)Wm1;

    float x = fminf(fmaxf((t.x + 1.0f) * 0.5f * fw, 0.0f), fw);
    float y = fminf(fmaxf((t.y + 1.0f) * 0.5f * fw, 0.0f), fw);
    float d = fminf(fmaxf((z + 1.0f) * 0.5f * 7.0f, 0.0f), 7.0f);

    int x0 = (int)x, y0 = (int)y, d0 = (int)d;
    int x1 = min(x0 + 1, Wm1), y1 = min(y0 + 1, Wm1), d1 = min(d0 + 1, 7);
    float wx = x - (float)x0, wy = y - (float)y0, wd = d - (float)d0;

    float w_d[2] = {1.0f - wd, wd};
    float w_y[2] = {1.0f - wy, wy};
    int   ds[2]  = {d0, d1};
    int   ys[2]  = {y0, y1};

#pragma unroll
    for (int c = 0; c < C_CH; ++c) {
        float res = 0.0f;
#pragma unroll
        for (int a = 0; a < 2; ++a)
#pragma unroll
            for (int b = 0; b < 2; ++b) {
                float w = w_d[a] * w_y[b];
                const float* base =
                    tex + ((size_t)ds[a] * C_CH + c) * W * W + (size_t)ys[b] * W;
                float va = base[x0];
                float vb = base[x1];
                res += w * (va + wx * (vb - va));
            }
        out[(size_t)c * R_TOTAL + i] = res;
    }
}

extern "C" void kernel_launch(void* const* d_in, const int* in_sizes, int n_in,
                              void* d_out, int out_size, void* d_ws, size_t ws_size,
                              hipStream_t stream) {
    const float* uv   = (const float*)d_in[0];
    const int*   idcs = (const int*)d_in[1];
    const float* sid  = (const float*)d_in[2];
    const float* tex0 = (const float*)d_in[3];
    const float* tex1 = (const float*)d_in[4];
    float*       out  = (float*)d_out;

    const size_t n0 = (size_t)M_DEPTH * C_CH * 512 * 512;  // 33,554,432 elems
    const size_t n1 = (size_t)M_DEPTH * C_CH * 256 * 256;  //  8,388,608 elems
    const size_t need = (n0 + n1) * sizeof(__half);        // ~84 MiB

    if (ws_size >= need) {
        __half* p0 = (__half*)d_ws;
        __half* p1 = p0 + n0;
        repack_fp16_kernel<<<(M_DEPTH * 512 * 512) / 256, 256, 0, stream>>>(tex0, p0, 18);
        repack_fp16_kernel<<<(M_DEPTH * 256 * 256) / 256, 256, 0, stream>>>(tex1, p1, 16);
        sample_packed_fp16<<<R_TOTAL / 512, 256, 0, stream>>>(uv, idcs, sid, p0, p1, out);
    } else {
        sample_direct<<<R_TOTAL / 256, 256, 0, stream>>>((const float2*)uv, idcs, sid,
                                                         tex0, tex1, out);
    }
}

// Round 3
// 267.801 us; speedup vs baseline: 1.6194x; 1.6194x over previous
//
#include <hip/hip_runtime.h>
#include <hip/hip_fp16.h>

#define R_TOTAL 2097152
#define M_DEPTH 8
#define C_CH 16

// One texel entry in the dup-packed layout: 64 bytes =
//   [ch0..15 @ x] (fp16, 32B) | [ch0..15 @ min(x+1,W-1)] (fp16, 32B)
struct C32 { float4 q[4]; };

// ---------------------------------------------------------------------------
// Repack [M, C, H, W] f32 -> [M, H, W, 2, C] fp16 with x-neighbor duplication.
// One thread per (m, y, x): 32 coalesced plane reads, one 64B store.
// ---------------------------------------------------------------------------
__global__ __launch_bounds__(256) void repack_dup_fp16(const float* __restrict__ src,
                                                       __half* __restrict__ dst,
                                                       int lgW) {
    int t = blockIdx.x * blockDim.x + threadIdx.x;   // index over M*H*W
    int W  = 1 << lgW;
    int HW = 1 << (2 * lgW);
    int m  = t >> (2 * lgW);
    int p  = t & (HW - 1);                           // y*W + x
    int x  = p & (W - 1);
    int x1off = (x == W - 1) ? 0 : 1;

    const float* s = src + (size_t)m * C_CH * HW + p;
    union { __half h[2 * C_CH]; float4 f[4]; } u;
#pragma unroll
    for (int c = 0; c < C_CH; ++c) {
        u.h[c]        = __float2half(s[(size_t)c * HW]);
        u.h[C_CH + c] = __float2half(s[(size_t)c * HW + x1off]);
    }
    float4* d4 = (float4*)(dst + (size_t)t * 2 * C_CH);
#pragma unroll
    for (int r = 0; r < 4; ++r) d4[r] = u.f[r];
}

// ---------------------------------------------------------------------------
// Sampler on dup-packed fp16 textures. One thread per sample, 4 line loads.
// ---------------------------------------------------------------------------
__device__ inline void corner_accum(const C32& c, float w, float wx,
                                    float acc[C_CH]) {
    const __half2* pa = (const __half2*)&c.q[0];   // ch @ x0
    const __half2* pb = (const __half2*)&c.q[2];   // ch @ x1
#pragma unroll
    for (int k = 0; k < 8; ++k) {
        float2 fa = __half22float2(pa[k]);
        float2 fb = __half22float2(pb[k]);
        acc[2 * k + 0] += w * (fa.x + wx * (fb.x - fa.x));
        acc[2 * k + 1] += w * (fa.y + wx * (fb.y - fa.y));
    }
}

__global__ __launch_bounds__(256) void sample_dup_fp16(
    const float2* __restrict__ uv, const int* __restrict__ idcs,
    const float* __restrict__ sid, const __half* __restrict__ tex0p,
    const __half* __restrict__ tex1p, float* __restrict__ out) {
    int i = blockIdx.x * blockDim.x + threadIdx.x;

    float2 t  = uv[i];
    float  z  = sid[i];
    int which = idcs[i];

    const __half* tex = (which == 0) ? tex0p : tex1p;
    int   Wm1 = (which == 0) ? 511 : 255;
    int   W   = Wm1 + 1;
    float fw  = (float)Wm1;

    float x = fminf(fmaxf((t.x + 1.0f) * 0.5f * fw, 0.0f), fw);
    float y = fminf(fmaxf((t.y + 1.0f) * 0.5f * fw, 0.0f), fw);
    float d = fminf(fmaxf((z + 1.0f) * 0.5f * 7.0f, 0.0f), 7.0f);

    int x0 = (int)x, y0 = (int)y, d0 = (int)d;
    int y1 = min(y0 + 1, Wm1), d1 = min(d0 + 1, 7);
    float wx = x - (float)x0, wy = y - (float)y0, wd = d - (float)d0;

    float w_d[2] = {1.0f - wd, wd};
    float w_y[2] = {1.0f - wy, wy};
    int   ds[2]  = {d0, d1};
    int   ys[2]  = {y0, y1};

    // Issue all 4 corner-line loads (16 x dwordx4, 4 distinct 64B lines).
    C32 cv[2][2];
#pragma unroll
    for (int a = 0; a < 2; ++a)
#pragma unroll
        for (int b = 0; b < 2; ++b) {
            const C32* e = (const C32*)(tex +
                ((size_t)(ds[a] * W + ys[b]) * W + x0) * (2 * C_CH));
            cv[a][b] = *e;
        }

    float acc[C_CH];
#pragma unroll
    for (int c = 0; c < C_CH; ++c) acc[c] = 0.0f;
#pragma unroll
    for (int a = 0; a < 2; ++a)
#pragma unroll
        for (int b = 0; b < 2; ++b)
            corner_accum(cv[a][b], w_d[a] * w_y[b], wx, acc);

#pragma unroll
    for (int c = 0; c < C_CH; ++c)
        out[(size_t)c * R_TOTAL + i] = acc[c];
}

// ---------------------------------------------------------------------------
// Secondary path (R1 winner): f32 channel-last pack, 8 lines/sample.
// ---------------------------------------------------------------------------
__global__ __launch_bounds__(256) void repack_f32(const float* __restrict__ src,
                                                  float* __restrict__ dst,
                                                  int lgHW) {
    int t = blockIdx.x * blockDim.x + threadIdx.x;
    int HW = 1 << lgHW;
    int m  = t >> lgHW;
    int p  = t & (HW - 1);
    const float* s = src + (size_t)m * C_CH * HW + p;
    float v[C_CH];
#pragma unroll
    for (int c = 0; c < C_CH; ++c) v[c] = s[(size_t)c * HW];
    float4* d4 = (float4*)(dst + (size_t)t * C_CH);
#pragma unroll
    for (int r = 0; r < 4; ++r)
        d4[r] = make_float4(v[4 * r + 0], v[4 * r + 1], v[4 * r + 2], v[4 * r + 3]);
}

__global__ __launch_bounds__(256) void sample_packed_f32(
    const float2* __restrict__ uv, const int* __restrict__ idcs,
    const float* __restrict__ sid, const float* __restrict__ tex0p,
    const float* __restrict__ tex1p, float* __restrict__ out) {
    int i = blockIdx.x * blockDim.x + threadIdx.x;

    float2 t  = uv[i];
    float  z  = sid[i];
    int which = idcs[i];

    const float* tex = (which == 0) ? tex0p : tex1p;
    int   Wm1 = (which == 0) ? 511 : 255;
    int   W   = Wm1 + 1;
    float fw  = (float)Wm1;

    float x = fminf(fmaxf((t.x + 1.0f) * 0.5f * fw, 0.0f), fw);
    float y = fminf(fmaxf((t.y + 1.0f) * 0.5f * fw, 0.0f), fw);
    float d = fminf(fmaxf((z + 1.0f) * 0.5f * 7.0f, 0.0f), 7.0f);

    int x0 = (int)x, y0 = (int)y, d0 = (int)d;
    int x1 = min(x0 + 1, Wm1), y1 = min(y0 + 1, Wm1), d1 = min(d0 + 1, 7);
    float wx = x - (float)x0, wy = y - (float)y0, wd = d - (float)d0;

    float acc[C_CH];
#pragma unroll
    for (int c = 0; c < C_CH; ++c) acc[c] = 0.0f;

    float w_d[2] = {1.0f - wd, wd};
    float w_y[2] = {1.0f - wy, wy};
    int   ds[2]  = {d0, d1};
    int   ys[2]  = {y0, y1};

#pragma unroll
    for (int a = 0; a < 2; ++a)
#pragma unroll
        for (int b = 0; b < 2; ++b) {
            float w = w_d[a] * w_y[b];
            const float* base = tex + (size_t)(ds[a] * W + ys[b]) * W * C_CH;
            const float4* pa = (const float4*)(base + (size_t)x0 * C_CH);
            const float4* pb = (const float4*)(base + (size_t)x1 * C_CH);
#pragma unroll
            for (int r = 0; r < 4; ++r) {
                float4 va = pa[r];
                float4 vb = pb[r];
                acc[4 * r + 0] += w * (va.x + wx * (vb.x - va.x));
                acc[4 * r + 1] += w * (va.y + wx * (vb.y - va.y));
                acc[4 * r + 2] += w * (va.z + wx * (vb.z - va.z));
                acc[4 * r + 3] += w * (va.w + wx * (vb.w - va.w));
            }
        }

#pragma unroll
    for (int c = 0; c < C_CH; ++c)
        out[(size_t)c * R_TOTAL + i] = acc[c];
}

// ---------------------------------------------------------------------------
// Tertiary fallback: sample directly from [M, C, H, W] f32.
// ---------------------------------------------------------------------------
__global__ __launch_bounds__(256) void sample_direct(
    const float2* __restrict__ uv, const int* __restrict__ idcs,
    const float* __restrict__ sid, const float* __restrict__ tex0,
    const float* __restrict__ tex1, float* __restrict__ out) {
    int i = blockIdx.x * blockDim.x + threadIdx.x;

    float2 t  = uv[i];
    float  z  = sid[i];
    int which = idcs[i];

    const float* tex = (which == 0) ? tex0 : tex1;
    int   Wm1 = (which == 0) ? 511 : 255;
    int   W   = Wm1 + 1;
    float fw  = (float)Wm1;

    float x = fminf(fmaxf((t.x + 1.0f) * 0.5f * fw, 0.0f), fw);
    float y = fminf(fmaxf((t.y + 1.0f) * 0.5f * fw, 0.0f), fw);
    float d = fminf(fmaxf((z + 1.0f) * 0.5f * 7.0f, 0.0f), 7.0f);

    int x0 = (int)x, y0 = (int)y, d0 = (int)d;
    int x1 = min(x0 + 1, Wm1), y1 = min(y0 + 1, Wm1), d1 = min(d0 + 1, 7);
    float wx = x - (float)x0, wy = y - (float)y0, wd = d - (float)d0;

    float w_d[2] = {1.0f - wd, wd};
    float w_y[2] = {1.0f - wy, wy};
    int   ds[2]  = {d0, d1};
    int   ys[2]  = {y0, y1};

#pragma unroll
    for (int c = 0; c < C_CH; ++c) {
        float res = 0.0f;
#pragma unroll
        for (int a = 0; a < 2; ++a)
#pragma unroll
            for (int b = 0; b < 2; ++b) {
                float w = w_d[a] * w_y[b];
                const float* base =
                    tex + ((size_t)ds[a] * C_CH + c) * W * W + (size_t)ys[b] * W;
                float va = base[x0];
                float vb = base[x1];
                res += w * (va + wx * (vb - va));
            }
        out[(size_t)c * R_TOTAL + i] = res;
    }
}

extern "C" void kernel_launch(void* const* d_in, const int* in_sizes, int n_in,
                              void* d_out, int out_size, void* d_ws, size_t ws_size,
                              hipStream_t stream) {
    const float2* uv   = (const float2*)d_in[0];
    const int*    idcs = (const int*)d_in[1];
    const float*  sid  = (const float*)d_in[2];
    const float*  tex0 = (const float*)d_in[3];
    const float*  tex1 = (const float*)d_in[4];
    float*        out  = (float*)d_out;

    const size_t e0 = (size_t)M_DEPTH * 512 * 512;   // entries in tex0
    const size_t e1 = (size_t)M_DEPTH * 256 * 256;   // entries in tex1
    const size_t need_dup = (e0 + e1) * 2 * C_CH * sizeof(__half);  // ~168 MiB
    const size_t need_f32 = (e0 + e1) * C_CH * sizeof(float);       // ~160 MiB

    if (ws_size >= need_dup) {
        __half* p0 = (__half*)d_ws;
        __half* p1 = p0 + e0 * 2 * C_CH;
        repack_dup_fp16<<<(int)(e0 / 256), 256, 0, stream>>>(tex0, p0, 9);
        repack_dup_fp16<<<(int)(e1 / 256), 256, 0, stream>>>(tex1, p1, 8);
        sample_dup_fp16<<<R_TOTAL / 256, 256, 0, stream>>>(uv, idcs, sid, p0, p1, out);
    } else if (ws_size >= need_f32) {
        float* p0 = (float*)d_ws;
        float* p1 = p0 + e0 * C_CH;
        repack_f32<<<(int)(e0 / 256), 256, 0, stream>>>(tex0, p0, 18);
        repack_f32<<<(int)(e1 / 256), 256, 0, stream>>>(tex1, p1, 16);
        sample_packed_f32<<<R_TOTAL / 256, 256, 0, stream>>>(uv, idcs, sid, p0, p1, out);
    } else {
        sample_direct<<<R_TOTAL / 256, 256, 0, stream>>>(uv, idcs, sid, tex0, tex1, out);
    }
}